// Round 7
// baseline (2049.717 us; speedup 1.0000x reference)
//
#include <hip/hip_runtime.h>
#include <hip/hip_bf16.h>
#include <math.h>

#define NBATCH 64
#define TSEQ   1000
#define DIN    257
#define HID    128
#define GATES  512   // 4*HID
#define CH     40    // pipeline chunk (timesteps); 25 chunks of 40 = 1000
#define NCHUNK 25

typedef _Float16 h2    __attribute__((ext_vector_type(2)));
typedef _Float16 h4    __attribute__((ext_vector_type(4)));
typedef _Float16 half8 __attribute__((ext_vector_type(8)));
typedef float    f32x4 __attribute__((ext_vector_type(4)));

__device__ __forceinline__ float fast_sigmoid(float x) {
    return __builtin_amdgcn_rcpf(1.f + __expf(-x));
}
// branchless tanh: tanh(x) = 1 - 2/(exp(2x)+1), exact identity, valid all x
__device__ __forceinline__ float fast_tanh(float x) {
    const float e = __expf(2.f * x);
    return 1.f - 2.f * __builtin_amdgcn_rcpf(e + 1.f);
}
// R3/R6-proven acquire poll
__device__ __forceinline__ void wait_flag(const int* f, int need) {
    while (__hip_atomic_load(f, __ATOMIC_ACQUIRE, __HIP_MEMORY_SCOPE_AGENT) < need)
        __builtin_amdgcn_s_sleep(2);
}
__device__ __forceinline__ half8 cvt8(const float* p) {
    const float4 a = *(const float4*)p;
    const float4 b = *(const float4*)(p + 4);
    half8 t;
    t[0] = (_Float16)a.x; t[1] = (_Float16)a.y;
    t[2] = (_Float16)a.z; t[3] = (_Float16)a.w;
    t[4] = (_Float16)b.x; t[5] = (_Float16)b.y;
    t[6] = (_Float16)b.z; t[7] = (_Float16)b.w;
    return t;
}

// ---------------------------------------------------------------------------
// f16 MFMA GEMM (unchanged): C = act(A @ W^T + b1 (+b2)), fp32 I/O.
// Now used ONLY for pre1 (K=257).
// ---------------------------------------------------------------------------
#define BM 128
#define BN 64
#define BK 64
#define LDK 88

template<int ACT>
__global__ __launch_bounds__(256) void gemm_mfma(
    const float* __restrict__ A, const float* __restrict__ W,
    const float* __restrict__ b1, const float* __restrict__ b2,
    float* __restrict__ C, int M, int K, int Ncols)
{
    __shared__ _Float16 As[BM][LDK];
    __shared__ _Float16 Ws[BN][LDK];

    const int tid  = threadIdx.x;
    const int wave = tid >> 6;
    const int lane = tid & 63;
    const int r    = lane & 15;
    const int q    = lane >> 4;
    const int m0   = blockIdx.y * BM;
    const int n0   = blockIdx.x * BN;
    const int wm   = (wave >> 1) * 64;
    const int wn   = (wave & 1) * 32;

    const int r16 = tid >> 4;
    const int c4  = (tid & 15) * 4;

    f32x4 acc[4][2];
#pragma unroll
    for (int i = 0; i < 4; ++i)
#pragma unroll
        for (int j = 0; j < 2; ++j) acc[i][j] = f32x4{0.f, 0.f, 0.f, 0.f};

    for (int kc = 0; kc < K; kc += BK) {
        const int kg = kc + c4;
        const bool vec_ok = (kg + 4 <= K);

#pragma unroll
        for (int it = 0; it < 8; ++it) {
            const int row = it * 16 + r16;
            const float* src = A + (size_t)(m0 + row) * K + kg;
            _Float16 tmp[4];
            if (vec_ok) {
                const float4 u = *(const float4*)src;
                tmp[0] = (_Float16)u.x; tmp[1] = (_Float16)u.y;
                tmp[2] = (_Float16)u.z; tmp[3] = (_Float16)u.w;
            } else {
#pragma unroll
                for (int j = 0; j < 4; ++j)
                    tmp[j] = (kg + j < K) ? (_Float16)src[j] : (_Float16)0.f;
            }
            *(h4*)&As[row][c4] = *(h4*)tmp;
        }
#pragma unroll
        for (int it = 0; it < 4; ++it) {
            const int row  = it * 16 + r16;
            const int wrow = n0 + row;
            _Float16 tmp[4] = {(_Float16)0.f, (_Float16)0.f, (_Float16)0.f, (_Float16)0.f};
            if (wrow < Ncols) {
                const float* src = W + (size_t)wrow * K + kg;
                if (vec_ok) {
                    const float4 u = *(const float4*)src;
                    tmp[0] = (_Float16)u.x; tmp[1] = (_Float16)u.y;
                    tmp[2] = (_Float16)u.z; tmp[3] = (_Float16)u.w;
                } else {
#pragma unroll
                    for (int j = 0; j < 4; ++j)
                        tmp[j] = (kg + j < K) ? (_Float16)src[j] : (_Float16)0.f;
                }
            }
            *(h4*)&Ws[row][c4] = *(h4*)tmp;
        }
        __syncthreads();

#pragma unroll
        for (int s = 0; s < 2; ++s) {
            const int kb = s * 32 + q * 8;
            half8 af[4], wfr[2];
#pragma unroll
            for (int i = 0; i < 4; ++i)
                af[i] = *(const half8*)&As[wm + i * 16 + r][kb];
#pragma unroll
            for (int j = 0; j < 2; ++j)
                wfr[j] = *(const half8*)&Ws[wn + j * 16 + r][kb];
#pragma unroll
            for (int i = 0; i < 4; ++i)
#pragma unroll
                for (int j = 0; j < 2; ++j)
                    acc[i][j] = __builtin_amdgcn_mfma_f32_16x16x32_f16(
                        af[i], wfr[j], acc[i][j], 0, 0, 0);
        }
        __syncthreads();
    }

#pragma unroll
    for (int i = 0; i < 4; ++i) {
#pragma unroll
        for (int j = 0; j < 2; ++j) {
            const int col = n0 + wn + j * 16 + r;
            if (col < Ncols) {
                const float bias = b1[col] + (b2 ? b2[col] : 0.f);
#pragma unroll
                for (int reg = 0; reg < 4; ++reg) {
                    const int row = m0 + wm + i * 16 + q * 4 + reg;
                    float v = acc[i][j][reg] + bias;
                    if (ACT == 1) v = fast_sigmoid(v);
                    C[(size_t)row * Ncols + col] = v;
                }
            }
        }
    }
}

// ---------------------------------------------------------------------------
// R7: R6's proven pipeline + fence, plus:
//  (a) mask GEMM (was K5, ~100us serialized) folded into the L2 blocks:
//      h2 chunk kept in LDS (h2ck); Wd staged once in LDS as f16 with XOR
//      swizzle (G4: row-major D=128 rows are same-bank; byte ^= (row&7)<<4);
//      at each chunk head, the PREVIOUS chunk's h2ck @ Wd^T + bd -> sigmoid
//      -> nontemporal mask stores. ~150 cyc/step, hidden in L2's ~500cyc
//      slack behind the L1 critical path. h2seq + K5 deleted.
//  (b) h1g + mask stores nontemporal: shrinks the dirty-L2 set the per-chunk
//      buffer_wbl2 (L1 critical path) must flush.
//  h1g moved to workspace bufB (mask region is now written concurrently).
// LDS: pre2ck 82560 + wd_lds 69632 + h2ck 10880 + hbuf 512 = 163584 <= 160KiB.
// ---------------------------------------------------------------------------
__global__ __launch_bounds__(256, 1) void lstm_mega(
    const float* __restrict__ pre1, const float* __restrict__ states_in,
    const float* __restrict__ Whh1, const float* __restrict__ Whh2,
    const float* __restrict__ Wih2, const float* __restrict__ bih2,
    const float* __restrict__ bhh2,
    const float* __restrict__ Wd, const float* __restrict__ bd,
    _Float16* __restrict__ h1g,        // [M][128] f16 handoff (in bufB)
    float* __restrict__ mask_out,      // [N][T][257] final output
    float* __restrict__ states_out, int* __restrict__ flags)
{
    const int layer = blockIdx.x >> 6;
    const int n     = blockIdx.x & 63;
    const int tid   = threadIdx.x;
    const int w     = tid >> 6;
    const int lane  = tid & 63;
    const int r     = lane & 15;
    const int q     = lane >> 4;
    const int b     = q & 1;
    const int j     = 32 * w + 16 * b + r;   // this lane's output index
    const int h_row0 = layer ? 128 : 0;

    __shared__ __align__(16) _Float16 hbuf[2][HID];           //    512 B
    __shared__ __align__(16) float    pre2ck[CH][GATES + 4];  //  82560 B
    __shared__ __align__(16) _Float16 wd_lds[272][HID];       //  69632 B
    __shared__ __align__(16) _Float16 h2ck[CH][136];          //  10880 B

    // ---- recurrence weights: wf[g][b2][s], row = 128g + 32w + 16b2 + r
    const float* Whh = layer ? Whh2 : Whh1;
    half8 wf[4][2][4];
#pragma unroll
    for (int g = 0; g < 4; ++g)
#pragma unroll
        for (int b2 = 0; b2 < 2; ++b2) {
            const float* src = Whh + (size_t)(128 * g + 32 * w + 16 * b2 + r) * HID + q * 8;
#pragma unroll
            for (int s = 0; s < 4; ++s) wf[g][b2][s] = cvt8(src + s * 32);
        }

    // ---- layer-2 extra: Wih2 B-frags + Wd LDS staging
    half8 wih[8][4];
    float bias2v[8];
    if (layer == 1) {
#pragma unroll
        for (int fi = 0; fi < 8; ++fi) {
            const int row = 128 * w + 16 * fi + r;
            const float* src = Wih2 + (size_t)row * HID + q * 8;
#pragma unroll
            for (int s = 0; s < 4; ++s) wih[fi][s] = cvt8(src + s * 32);
            bias2v[fi] = bih2[row] + bhh2[row];
        }
        // zero pad rows 257..271 (their MFMA outputs are never stored, but
        // keep them finite)
        for (int i = tid; i < 15 * HID; i += 256)
            wd_lds[257 + (i >> 7)][i & 127] = (_Float16)0.f;
        // stage Wd[257][128] f32 -> f16, XOR-swizzled: byte ^= (row&7)<<4
        for (int i = tid; i < 257 * 32; i += 256) {
            const int row = i >> 5, c4 = (i & 31) * 4;
            const float4 u = *(const float4*)(Wd + (size_t)row * HID + c4);
            _Float16 t4[4] = {(_Float16)u.x, (_Float16)u.y,
                              (_Float16)u.z, (_Float16)u.w};
            const int byte = row * 256 + ((c4 * 2) ^ ((row & 7) << 4));
            *(h4*)((char*)&wd_lds[0][0] + byte) = *(h4*)t4;
        }
    }

    float c_r = states_in[(size_t)(h_row0 + 64 + n) * HID + j];
    if (tid < HID)
        hbuf[0][tid] = (_Float16)states_in[(size_t)(h_row0 + n) * HID + tid];
    __syncthreads();

    // layer-1: pre1 prefetch registers
    const float* pre_n = pre1 + (size_t)n * TSEQ * GATES;
    float pc0 = 0.f, pc1 = 0.f, pc2 = 0.f, pc3 = 0.f;
    float pn0 = 0.f, pn1 = 0.f, pn2 = 0.f, pn3 = 0.f;
    if (layer == 0) {
        pc0 = pre_n[j];           pc1 = pre_n[j + 128];
        pc2 = pre_n[j + 256];     pc3 = pre_n[j + 384];
        pn0 = pre_n[GATES + j];       pn1 = pre_n[GATES + j + 128];
        pn2 = pre_n[GATES + j + 256]; pn3 = pre_n[GATES + j + 384];
    }

    const f32x4 Z = {0.f, 0.f, 0.f, 0.f};

    // mask fold for chunk c: prev chunk's h2ck @ Wd^T + bd -> sigmoid -> mask
    auto mask_fold = [&](int c) {
#pragma unroll
        for (int mt = 0; mt < 3; ++mt) {
            const int mrow = (mt < 2) ? (mt * 16 + r) : (32 + (r & 7));
            half8 ax[4];
#pragma unroll
            for (int s = 0; s < 4; ++s)
                ax[s] = *(const half8*)&h2ck[mrow][s * 32 + q * 8];
#pragma unroll
            for (int fi = 0; fi < 17; ++fi) {
                const int wrow = 16 * fi + r;
                half8 wb[4];
#pragma unroll
                for (int s = 0; s < 4; ++s) {
                    const int byte = wrow * 256 +
                        ((s * 64 + q * 16) ^ ((wrow & 7) << 4));
                    wb[s] = *(const half8*)((const char*)&wd_lds[0][0] + byte);
                }
                f32x4 g = __builtin_amdgcn_mfma_f32_16x16x32_f16(
                    ax[0], wb[0], Z, 0, 0, 0);
#pragma unroll
                for (int s = 1; s < 4; ++s)
                    g = __builtin_amdgcn_mfma_f32_16x16x32_f16(
                        ax[s], wb[s], g, 0, 0, 0);
                if (wrow < DIN && (mt < 2 || q < 2)) {
                    const float bias = bd[wrow];
#pragma unroll
                    for (int reg = 0; reg < 4; ++reg) {
                        const int tt = c * CH + mt * 16 + 4 * q + reg;
                        __builtin_nontemporal_store(
                            fast_sigmoid(g[reg] + bias),
                            mask_out + ((size_t)n * TSEQ + tt) * DIN + wrow);
                    }
                }
            }
        }
    };

    int cur = 0, ts = 0, ck = 0;   // step-within-chunk, chunk index

    for (int t = 0; t < TSEQ; ++t) {
        // ==== layer-2 chunk head ====
        if (layer == 1 && ts == 0) {
            if (ck > 0) mask_fold(ck - 1);   // h2ck of prev chunk still intact
            wait_flag(flags + n, ck + 1);    // ACQUIRE: h1g chunk ck visible
            const _Float16* hbase = h1g + ((size_t)n * TSEQ + (size_t)ck * CH) * HID;
#pragma unroll
            for (int mt = 0; mt < 3; ++mt) {
                const int mrow = (mt < 2) ? (mt * 16 + r) : (32 + (r & 7));
                const _Float16* src = hbase + (size_t)mrow * HID + q * 8;
                half8 ax[4];
#pragma unroll
                for (int s = 0; s < 4; ++s)
                    ax[s] = *(const half8*)(src + s * 32);
                f32x4 gacc[8];
#pragma unroll
                for (int fi = 0; fi < 8; ++fi)
                    gacc[fi] = __builtin_amdgcn_mfma_f32_16x16x32_f16(
                        ax[0], wih[fi][0], Z, 0, 0, 0);
#pragma unroll
                for (int s = 1; s < 4; ++s)
#pragma unroll
                    for (int fi = 0; fi < 8; ++fi)
                        gacc[fi] = __builtin_amdgcn_mfma_f32_16x16x32_f16(
                            ax[s], wih[fi][s], gacc[fi], 0, 0, 0);
                if (mt < 2 || q < 2) {
#pragma unroll
                    for (int fi = 0; fi < 8; ++fi)
#pragma unroll
                        for (int reg = 0; reg < 4; ++reg)
                            pre2ck[mt * 16 + 4 * q + reg][128 * w + 16 * fi + r] =
                                gacc[fi][reg] + bias2v[fi];
                }
            }
            __syncthreads();
        }

        // ==== gate pre-activations ====
        float p0, p1, p2, p3;
        if (layer == 0) {
            p0 = pc0; p1 = pc1; p2 = pc2; p3 = pc3;
            pc0 = pn0; pc1 = pn1; pc2 = pn2; pc3 = pn3;
            if (t + 2 < TSEQ) {
                const float* pp = pre_n + (size_t)(t + 2) * GATES + j;
                pn0 = pp[0]; pn1 = pp[128]; pn2 = pp[256]; pn3 = pp[384];
            }
        } else {
            p0 = pre2ck[ts][j];
            p1 = pre2ck[ts][j + 128];
            p2 = pre2ck[ts][j + 256];
            p3 = pre2ck[ts][j + 384];
        }

        // ==== recurrent matvec (MFMA) ====
        half8 hx[4];
#pragma unroll
        for (int s = 0; s < 4; ++s)
            hx[s] = *(const half8*)&hbuf[cur][s * 32 + q * 8];

        f32x4 acc[4][2];
#pragma unroll
        for (int g = 0; g < 4; ++g)
#pragma unroll
            for (int b2 = 0; b2 < 2; ++b2)
                acc[g][b2] = __builtin_amdgcn_mfma_f32_16x16x32_f16(
                    hx[0], wf[g][b2][0], Z, 0, 0, 0);
#pragma unroll
        for (int s = 1; s < 4; ++s)
#pragma unroll
            for (int g = 0; g < 4; ++g)
#pragma unroll
                for (int b2 = 0; b2 < 2; ++b2)
                    acc[g][b2] = __builtin_amdgcn_mfma_f32_16x16x32_f16(
                        hx[s], wf[g][b2][s], acc[g][b2], 0, 0, 0);

        const float A0 = (b ? acc[0][1][0] : acc[0][0][0]) + p0;
        const float A1 = (b ? acc[1][1][0] : acc[1][0][0]) + p1;
        const float A2 = (b ? acc[2][1][0] : acc[2][0][0]) + p2;
        const float A3 = (b ? acc[3][1][0] : acc[3][0][0]) + p3;

        const float gi = fast_sigmoid(A0);
        const float gf = fast_sigmoid(A1);
        const float gg = fast_tanh(A2);
        const float go = fast_sigmoid(A3);

        const float cn = gf * c_r + gi * gg;
        const float hh = go * fast_tanh(cn);
        c_r = cn;

        // ==== state writes ====
        if (q < 2) {
            hbuf[cur ^ 1][j] = (_Float16)hh;
            if (t == TSEQ - 1)
                states_out[(size_t)(h_row0 + 64 + n) * HID + j] = cn;
        } else {
            if (layer == 0)
                __builtin_nontemporal_store((_Float16)hh,
                    &h1g[((size_t)n * TSEQ + t) * HID + j]);
            else
                h2ck[ts][j] = (_Float16)hh;
            if (t == TSEQ - 1)
                states_out[(size_t)(h_row0 + n) * HID + j] = hh;
        }
        __syncthreads();   // drains vmcnt(0) per wave: chunk stores complete

        // ==== layer-1 chunk tail: publish chunk ck (proven fence recipe) ====
        if (layer == 0 && ts == CH - 1 && tid == 0) {
            __threadfence();   // agent release (wbl2): h1g chunk ck visible
            __hip_atomic_store(flags + n, ck + 1,
                               __ATOMIC_RELAXED, __HIP_MEMORY_SCOPE_AGENT);
        }

        if (++ts == CH) { ts = 0; ++ck; }
        cur ^= 1;
    }

    // last chunk's mask fold (h2ck complete; in-loop barrier already passed)
    if (layer == 1) mask_fold(NCHUNK - 1);
}

// ---------------------------------------------------------------------------
extern "C" void kernel_launch(void* const* d_in, const int* in_sizes, int n_in,
                              void* d_out, int out_size, void* d_ws, size_t ws_size,
                              hipStream_t stream)
{
    const float* x     = (const float*)d_in[0];
    const float* st_in = (const float*)d_in[1];
    const float* Wih1  = (const float*)d_in[2];
    const float* Whh1  = (const float*)d_in[3];
    const float* bih1  = (const float*)d_in[4];
    const float* bhh1  = (const float*)d_in[5];
    const float* Wih2  = (const float*)d_in[6];
    const float* Whh2  = (const float*)d_in[7];
    const float* bih2  = (const float*)d_in[8];
    const float* bhh2  = (const float*)d_in[9];
    const float* Wd    = (const float*)d_in[10];
    const float* bd    = (const float*)d_in[11];

    float* out_mask   = (float*)d_out;
    float* out_states = (float*)d_out + (size_t)NBATCH * TSEQ * DIN;

    const int M = NBATCH * TSEQ;
    float* bufA = (float*)d_ws;               // [M,512] pre1
    float* bufB = bufA + (size_t)M * GATES;   // h1g (f16) + flags

    // h1g: [M][128] f16 = 16.4MB in first half of bufB; flags after it.
    _Float16* h1g = (_Float16*)bufB;
    int* flags = (int*)(bufB + (size_t)M * (HID / 2));
    hipMemsetAsync(flags, 0, 64 * sizeof(int), stream);

    // K1: pre1 = x @ Wih1^T + bih1 + bhh1   (M=64000, K=257, N=512)
    gemm_mfma<0><<<dim3(GATES / BN, M / BM), 256, 0, stream>>>(
        x, Wih1, bih1, bhh1, bufA, M, DIN, GATES);

    // fused pipelined L1 rec -> h1 handoff -> (pre2 + mask on reader) -> done
    lstm_mega<<<128, 256, 0, stream>>>(
        bufA, st_in, Whh1, Whh2, Wih2, bih2, bhh2, Wd, bd,
        h1g, out_mask, out_states, flags);
}

// Round 8
// 2021.186 us; speedup vs baseline: 1.0141x; 1.0141x over previous
//
#include <hip/hip_runtime.h>
#include <hip/hip_bf16.h>
#include <math.h>

#define NBATCH 64
#define TSEQ   1000
#define DIN    257
#define HID    128
#define GATES  512   // 4*HID
#define CHK    40    // pipeline chunk (timesteps)
#define NCHUNK 25
#define GPC    16    // chains per rec block (A/C classes)

typedef _Float16 h2    __attribute__((ext_vector_type(2)));
typedef _Float16 h4    __attribute__((ext_vector_type(4)));
typedef _Float16 half8 __attribute__((ext_vector_type(8)));
typedef float    f32x4 __attribute__((ext_vector_type(4)));

__device__ __forceinline__ float fast_sigmoid(float x) {
    return __builtin_amdgcn_rcpf(1.f + __expf(-x));
}
// branchless tanh: tanh(x) = 1 - 2/(exp(2x)+1), exact identity, valid all x
__device__ __forceinline__ float fast_tanh(float x) {
    const float e = __expf(2.f * x);
    return 1.f - 2.f * __builtin_amdgcn_rcpf(e + 1.f);
}
// R3/R6-proven acquire poll
__device__ __forceinline__ void wait_flag(const int* f, int need) {
    while (__hip_atomic_load(f, __ATOMIC_ACQUIRE, __HIP_MEMORY_SCOPE_AGENT) < need)
        __builtin_amdgcn_s_sleep(2);
}
__device__ __forceinline__ half8 cvt8(const float* p) {
    const float4 a = *(const float4*)p;
    const float4 b = *(const float4*)(p + 4);
    half8 t;
    t[0] = (_Float16)a.x; t[1] = (_Float16)a.y;
    t[2] = (_Float16)a.z; t[3] = (_Float16)a.w;
    t[4] = (_Float16)b.x; t[5] = (_Float16)b.y;
    t[6] = (_Float16)b.z; t[7] = (_Float16)b.w;
    return t;
}

// ---------------------------------------------------------------------------
// f16 MFMA GEMM (unchanged, proven): C = act(A @ W^T + b1 (+b2)), fp32 I/O.
// Used for pre1 (K=257) and the final mask GEMM (K5).
// ---------------------------------------------------------------------------
#define BM 128
#define BN 64
#define BK 64
#define LDK 88

template<int ACT>
__global__ __launch_bounds__(256) void gemm_mfma(
    const float* __restrict__ A, const float* __restrict__ W,
    const float* __restrict__ b1, const float* __restrict__ b2,
    float* __restrict__ C, int M, int K, int Ncols)
{
    __shared__ _Float16 As[BM][LDK];
    __shared__ _Float16 Ws[BN][LDK];

    const int tid  = threadIdx.x;
    const int wave = tid >> 6;
    const int lane = tid & 63;
    const int r    = lane & 15;
    const int q    = lane >> 4;
    const int m0   = blockIdx.y * BM;
    const int n0   = blockIdx.x * BN;
    const int wm   = (wave >> 1) * 64;
    const int wn   = (wave & 1) * 32;

    const int r16 = tid >> 4;
    const int c4  = (tid & 15) * 4;

    f32x4 acc[4][2];
#pragma unroll
    for (int i = 0; i < 4; ++i)
#pragma unroll
        for (int j = 0; j < 2; ++j) acc[i][j] = f32x4{0.f, 0.f, 0.f, 0.f};

    for (int kc = 0; kc < K; kc += BK) {
        const int kg = kc + c4;
        const bool vec_ok = (kg + 4 <= K);

#pragma unroll
        for (int it = 0; it < 8; ++it) {
            const int row = it * 16 + r16;
            const float* src = A + (size_t)(m0 + row) * K + kg;
            _Float16 tmp[4];
            if (vec_ok) {
                const float4 u = *(const float4*)src;
                tmp[0] = (_Float16)u.x; tmp[1] = (_Float16)u.y;
                tmp[2] = (_Float16)u.z; tmp[3] = (_Float16)u.w;
            } else {
#pragma unroll
                for (int j = 0; j < 4; ++j)
                    tmp[j] = (kg + j < K) ? (_Float16)src[j] : (_Float16)0.f;
            }
            *(h4*)&As[row][c4] = *(h4*)tmp;
        }
#pragma unroll
        for (int it = 0; it < 4; ++it) {
            const int row  = it * 16 + r16;
            const int wrow = n0 + row;
            _Float16 tmp[4] = {(_Float16)0.f, (_Float16)0.f, (_Float16)0.f, (_Float16)0.f};
            if (wrow < Ncols) {
                const float* src = W + (size_t)wrow * K + kg;
                if (vec_ok) {
                    const float4 u = *(const float4*)src;
                    tmp[0] = (_Float16)u.x; tmp[1] = (_Float16)u.y;
                    tmp[2] = (_Float16)u.z; tmp[3] = (_Float16)u.w;
                } else {
#pragma unroll
                    for (int j = 0; j < 4; ++j)
                        tmp[j] = (kg + j < K) ? (_Float16)src[j] : (_Float16)0.f;
                }
            }
            *(h4*)&Ws[row][c4] = *(h4*)tmp;
        }
        __syncthreads();

#pragma unroll
        for (int s = 0; s < 2; ++s) {
            const int kb = s * 32 + q * 8;
            half8 af[4], wfr[2];
#pragma unroll
            for (int i = 0; i < 4; ++i)
                af[i] = *(const half8*)&As[wm + i * 16 + r][kb];
#pragma unroll
            for (int j = 0; j < 2; ++j)
                wfr[j] = *(const half8*)&Ws[wn + j * 16 + r][kb];
#pragma unroll
            for (int i = 0; i < 4; ++i)
#pragma unroll
                for (int j = 0; j < 2; ++j)
                    acc[i][j] = __builtin_amdgcn_mfma_f32_16x16x32_f16(
                        af[i], wfr[j], acc[i][j], 0, 0, 0);
        }
        __syncthreads();
    }

#pragma unroll
    for (int i = 0; i < 4; ++i) {
#pragma unroll
        for (int j = 0; j < 2; ++j) {
            const int col = n0 + wn + j * 16 + r;
            if (col < Ncols) {
                const float bias = b1[col] + (b2 ? b2[col] : 0.f);
#pragma unroll
                for (int reg = 0; reg < 4; ++reg) {
                    const int row = m0 + wm + i * 16 + q * 4 + reg;
                    float v = acc[i][j][reg] + bias;
                    if (ACT == 1) v = fast_sigmoid(v);
                    C[(size_t)row * Ncols + col] = v;
                }
            }
        }
    }
}

// ---------------------------------------------------------------------------
// R8: batched-MFMA recurrence pipeline. 72 blocks, 3 classes:
//   A (bid 0..3):   layer-1 rec, 16 chains/block. MFMA A-rows = 16 chains
//                   (no replication waste): D row=4q+reg=chain, col=r (the
//                   m89/m91-verified mapping already used by gemm_mfma).
//                   p loaded straight into the MFMA C-operand. Writes h1g
//                   (f16) per step; per 40-step chunk: fence + flag1[grp].
//   B (bid 4..67):  per-chain pre2 workers (R6's proven chunk GEMM): wait
//                   flag1, h1g chunk @ Wih2^T + bias -> pre2 written IN PLACE
//                   over pre1 (A is provably >=1 chunk ahead of B's writes),
//                   fence + flag2[n].
//   C (bid 68..71): layer-2 rec, same batched structure; waits flag2 of its
//                   16 chains with the R3-proven ck+2 gating (covers the
//                   depth-2 p-prefetch); writes h2seq f32 for K5.
// Sync is exactly R6's proven recipe (threadfence release + acquire poll);
// only 4+64 fences per chunk-period and none on the per-step path.
// hbuf is XOR-swizzled (T2, both-sides-same-involution) to avoid the 8-way
// read conflict of a linear [16][128] f16 layout.
// ---------------------------------------------------------------------------
__global__ __launch_bounds__(512, 1) void lstm_pipe(
    float* preA,                       // [M][512] pre1, overwritten by pre2
    const float* __restrict__ states_in,
    const float* __restrict__ Whh1, const float* __restrict__ Whh2,
    const float* __restrict__ Wih2, const float* __restrict__ bih2,
    const float* __restrict__ bhh2,
    _Float16* h1g,                     // [M][128] f16 handoff (mask region)
    float* __restrict__ h2seq,         // [M][128] f32 (ws) for K5
    float* __restrict__ states_out,
    int* flag1, int* flag2)
{
    const int bid  = blockIdx.x;
    const int tid  = threadIdx.x;
    const int u    = tid >> 6;     // wave 0..7
    const int lane = tid & 63;
    const int r    = lane & 15;
    const int q    = lane >> 4;
    const f32x4 Z  = {0.f, 0.f, 0.f, 0.f};

    __shared__ _Float16 hbuf[2][GPC * HID];   // 8 KB, XOR-swizzled rows

    if (bid >= 4 && bid < 68) {
        // ==================== class B: pre2 worker ====================
        const int n = bid - 4, grp = n >> 4;
        half8 wih[4][4];
        float bias2v[4];
#pragma unroll
        for (int fi = 0; fi < 4; ++fi) {
            const int row = 16 * (4 * u + fi) + r;
            const float* src = Wih2 + (size_t)row * HID + q * 8;
#pragma unroll
            for (int s = 0; s < 4; ++s) wih[fi][s] = cvt8(src + s * 32);
            bias2v[fi] = bih2[row] + bhh2[row];
        }
        for (int ck = 0; ck < NCHUNK; ++ck) {
            wait_flag(flag1 + grp, ck + 1);     // ACQUIRE: h1g chunk ck
            const _Float16* hbase = h1g + ((size_t)n * TSEQ + ck * CHK) * HID;
            float* pbase = preA + ((size_t)n * TSEQ + ck * CHK) * GATES;
#pragma unroll
            for (int mt = 0; mt < 3; ++mt) {
                const int mrow = (mt < 2) ? mt * 16 + r : 32 + (r & 7);
                const _Float16* src = hbase + (size_t)mrow * HID + q * 8;
                half8 ax[4];
#pragma unroll
                for (int s = 0; s < 4; ++s) ax[s] = *(const half8*)(src + s * 32);
                f32x4 gacc[4];
#pragma unroll
                for (int fi = 0; fi < 4; ++fi)
                    gacc[fi] = __builtin_amdgcn_mfma_f32_16x16x32_f16(
                        ax[0], wih[fi][0], Z, 0, 0, 0);
#pragma unroll
                for (int s = 1; s < 4; ++s)
#pragma unroll
                    for (int fi = 0; fi < 4; ++fi)
                        gacc[fi] = __builtin_amdgcn_mfma_f32_16x16x32_f16(
                            ax[s], wih[fi][s], gacc[fi], 0, 0, 0);
                if (mt < 2 || q < 2) {
#pragma unroll
                    for (int fi = 0; fi < 4; ++fi)
#pragma unroll
                        for (int reg = 0; reg < 4; ++reg)
                            pbase[(size_t)(mt * 16 + 4 * q + reg) * GATES +
                                  16 * (4 * u + fi) + r] = gacc[fi][reg] + bias2v[fi];
                }
            }
            __syncthreads();                    // drain stores (vmcnt 0)
            if (tid == 0) {
                __threadfence();                // agent release
                __hip_atomic_store(flag2 + n, ck + 1,
                                   __ATOMIC_RELAXED, __HIP_MEMORY_SCOPE_AGENT);
            }
        }
        return;
    }

    // ==================== class A (bid<4) / C (bid>=68) ====================
    const int layer  = (bid >= 68) ? 1 : 0;
    const int grp    = layer ? bid - 68 : bid;
    const int h_row0 = layer ? 128 : 0;
    const int j      = 16 * u + r;          // gate-col / hidden index
    const int n0     = 16 * grp + 4 * q;    // chain base (chain = n0+reg)
    const float* Whh = layer ? Whh2 : Whh1;

    // wf[g][s]: B-frag rows 128g + j, k = s*32 + q*8 .. +7  (64 VGPR)
    half8 wf[4][4];
#pragma unroll
    for (int g = 0; g < 4; ++g) {
        const float* src = Whh + (size_t)(128 * g + j) * HID + q * 8;
#pragma unroll
        for (int s = 0; s < 4; ++s) wf[g][s] = cvt8(src + s * 32);
    }

    // c-state: 4 chains' c at column j
    float c_r[4];
#pragma unroll
    for (int reg = 0; reg < 4; ++reg)
        c_r[reg] = states_in[(size_t)(h_row0 + 64 + n0 + reg) * HID + j];
    // h0 into swizzled hbuf
    for (int i = tid; i < GPC * HID; i += 512) {
        const int chain = i >> 7, jj = i & 127;
        const float v = states_in[(size_t)(h_row0 + 16 * grp + chain) * HID + jj];
        const int byte = chain * 256 + ((2 * jj) ^ ((chain & 7) << 4));
        *(_Float16*)((char*)&hbuf[0][0] + byte) = (_Float16)v;
    }
    __syncthreads();

    // p loader: P[g][reg] = pre[(chain n0+reg), t][128g + j]
    auto ldp = [&](int tt, float (&P)[4][4]) {
#pragma unroll
        for (int reg = 0; reg < 4; ++reg) {
            const float* pp = preA + ((size_t)(n0 + reg) * TSEQ + tt) * GATES + j;
#pragma unroll
            for (int g = 0; g < 4; ++g) P[g][reg] = pp[128 * g];
        }
    };

    if (layer) {  // gate the initial depth-2 prefetch (rows 0,1 + loads to 41)
        wait_flag(flag2 + 16 * grp + (tid & 15), NCHUNK < 2 ? NCHUNK : 2);
        __syncthreads();
    }

    float pA_[4][4], pB_[4][4];
    ldp(0, pA_);
    ldp(1, pB_);

    int cur = 0;

    auto step = [&](int t, float (&P)[4][4]) {
        // acc init = p (MFMA C-operand layout == D layout: row=4q+reg=chain)
        f32x4 acc[4];
#pragma unroll
        for (int g = 0; g < 4; ++g)
            acc[g] = f32x4{P[g][0], P[g][1], P[g][2], P[g][3]};
        if (t + 2 < TSEQ) ldp(t + 2, P);   // depth-2 prefetch into freed P

        half8 hx[4];
#pragma unroll
        for (int s = 0; s < 4; ++s) {
            const int byte = r * 256 + ((s * 64 + q * 16) ^ ((r & 7) << 4));
            hx[s] = *(const half8*)((const char*)&hbuf[cur][0] + byte);
        }
#pragma unroll
        for (int s = 0; s < 4; ++s)
#pragma unroll
            for (int g = 0; g < 4; ++g)
                acc[g] = __builtin_amdgcn_mfma_f32_16x16x32_f16(
                    hx[s], wf[g][s], acc[g], 0, 0, 0);

#pragma unroll
        for (int reg = 0; reg < 4; ++reg) {
            const float gi = fast_sigmoid(acc[0][reg]);
            const float gf = fast_sigmoid(acc[1][reg]);
            const float gg = fast_tanh(acc[2][reg]);
            const float go = fast_sigmoid(acc[3][reg]);
            const float cn = gf * c_r[reg] + gi * gg;
            const float hh = go * fast_tanh(cn);
            c_r[reg] = cn;
            const int row  = 4 * q + reg;
            const int byte = row * 256 + ((2 * j) ^ ((row & 7) << 4));
            *(_Float16*)((char*)&hbuf[cur ^ 1][0] + byte) = (_Float16)hh;
            if (layer == 0)
                h1g[((size_t)(n0 + reg) * TSEQ + t) * HID + j] = (_Float16)hh;
            else
                h2seq[((size_t)(n0 + reg) * TSEQ + t) * HID + j] = hh;
            if (t == TSEQ - 1) {
                states_out[(size_t)(h_row0 + n0 + reg) * HID + j]      = hh;
                states_out[(size_t)(h_row0 + 64 + n0 + reg) * HID + j] = cn;
            }
        }
        __syncthreads();   // drains h1g stores per wave (vmcnt 0) + hbuf ready

        if (layer == 0 && (t % CHK) == CHK - 1 && tid == 0) {
            __threadfence();   // agent release: h1g chunk visible
            __hip_atomic_store(flag1 + grp, t / CHK + 1,
                               __ATOMIC_RELAXED, __HIP_MEMORY_SCOPE_AGENT);
        }
        cur ^= 1;
    };

    for (int t = 0; t < TSEQ; t += 2) {
        if (layer && t > 0 && (t % CHK) == 0) {
            const int ck = t / CHK;
            const int need = (ck + 2 < NCHUNK) ? ck + 2 : NCHUNK;
            wait_flag(flag2 + 16 * grp + (tid & 15), need);  // all 16 chains
            __syncthreads();
        }
        step(t, pA_);
        step(t + 1, pB_);
    }
}

// ---------------------------------------------------------------------------
extern "C" void kernel_launch(void* const* d_in, const int* in_sizes, int n_in,
                              void* d_out, int out_size, void* d_ws, size_t ws_size,
                              hipStream_t stream)
{
    const float* x     = (const float*)d_in[0];
    const float* st_in = (const float*)d_in[1];
    const float* Wih1  = (const float*)d_in[2];
    const float* Whh1  = (const float*)d_in[3];
    const float* bih1  = (const float*)d_in[4];
    const float* bhh1  = (const float*)d_in[5];
    const float* Wih2  = (const float*)d_in[6];
    const float* Whh2  = (const float*)d_in[7];
    const float* bih2  = (const float*)d_in[8];
    const float* bhh2  = (const float*)d_in[9];
    const float* Wd    = (const float*)d_in[10];
    const float* bd    = (const float*)d_in[11];

    float* out_mask   = (float*)d_out;
    float* out_states = (float*)d_out + (size_t)NBATCH * TSEQ * DIN;

    const int M = NBATCH * TSEQ;
    float* bufA = (float*)d_ws;               // [M,512] pre1 -> pre2 in place
    float* bufB = bufA + (size_t)M * GATES;   // [M,128] h2seq f32

    // scratch in the mask output region (written by K5 strictly afterwards):
    //   h1g [M][128] f16 = 16.4MB at the start; flags at the tail.
    _Float16* h1g = (_Float16*)out_mask;
    int* fbase = (int*)(out_mask + (size_t)NBATCH * TSEQ * DIN) - 128;
    int* flag1 = fbase;        // [4]
    int* flag2 = fbase + 4;    // [64]
    hipMemsetAsync(fbase, 0, 128 * sizeof(int), stream);

    // K1: pre1 = x @ Wih1^T + bih1 + bhh1   (M=64000, K=257, N=512)
    gemm_mfma<0><<<dim3(GATES / BN, M / BM), 256, 0, stream>>>(
        x, Wih1, bih1, bhh1, bufA, M, DIN, GATES);

    // batched pipelined: L1 rec (A) -> pre2 workers (B) -> L2 rec (C)
    lstm_pipe<<<72, 512, 0, stream>>>(
        bufA, st_in, Whh1, Whh2, Wih2, bih2, bhh2,
        h1g, bufB, out_states, flag1, flag2);

    // K5: mask = sigmoid(h2seq @ Wd^T + bd)   (N=257)
    gemm_mfma<1><<<dim3((DIN + BN - 1) / BN, M / BM), 256, 0, stream>>>(
        bufB, Wd, bd, nullptr, out_mask, M, HID, DIN);
}

// Round 9
// 1071.216 us; speedup vs baseline: 1.9134x; 1.8868x over previous
//
#include <hip/hip_runtime.h>
#include <hip/hip_bf16.h>
#include <math.h>

#define NBATCH 64
#define TSEQ   1000
#define DIN    257
#define HID    128
#define GATES  512   // 4*HID
#define CH     40    // pipeline chunk (timesteps); 25 chunks of 40 = 1000
#define NCHUNK 25
#define KP1    320   // padded K for the pre1 GEMM (257 -> 320 = 5*64)

typedef _Float16 h2    __attribute__((ext_vector_type(2)));
typedef _Float16 h4    __attribute__((ext_vector_type(4)));
typedef _Float16 half8 __attribute__((ext_vector_type(8)));
typedef float    f32x4 __attribute__((ext_vector_type(4)));

__device__ __forceinline__ float fast_sigmoid(float x) {
    return __builtin_amdgcn_rcpf(1.f + __expf(-x));
}
// branchless tanh: tanh(x) = 1 - 2/(exp(2x)+1), exact identity, valid all x
__device__ __forceinline__ float fast_tanh(float x) {
    const float e = __expf(2.f * x);
    return 1.f - 2.f * __builtin_amdgcn_rcpf(e + 1.f);
}
// R3/R6-proven acquire poll
__device__ __forceinline__ void wait_flag(const int* f, int need) {
    while (__hip_atomic_load(f, __ATOMIC_ACQUIRE, __HIP_MEMORY_SCOPE_AGENT) < need)
        __builtin_amdgcn_s_sleep(2);
}
__device__ __forceinline__ half8 cvt8(const float* p) {
    const float4 a = *(const float4*)p;
    const float4 b = *(const float4*)(p + 4);
    half8 t;
    t[0] = (_Float16)a.x; t[1] = (_Float16)a.y;
    t[2] = (_Float16)a.z; t[3] = (_Float16)a.w;
    t[4] = (_Float16)b.x; t[5] = (_Float16)b.y;
    t[6] = (_Float16)b.z; t[7] = (_Float16)b.w;
    return t;
}

// ---------------------------------------------------------------------------
// cvt_rows: f32 [nrows][sk] -> f16 [nrows][dk], zero-padding cols sk..dk-1.
// One wave per row per pass; lane covers 4 consecutive cols (float4 -> h4).
// Memory-bound; ~18us total for all three arrays.
// ---------------------------------------------------------------------------
__global__ __launch_bounds__(256) void cvt_rows(
    const float* __restrict__ src, _Float16* __restrict__ dst,
    int nrows, int sk, int dk)
{
    const int lane   = threadIdx.x & 63;
    const int wid    = (blockIdx.x * 256 + threadIdx.x) >> 6;
    const int nw     = (gridDim.x * 256) >> 6;
    for (int row = wid; row < nrows; row += nw) {
        for (int c0 = 0; c0 < dk; c0 += 256) {
            const int c = c0 + lane * 4;
            if (c >= dk) continue;
            if (c + 4 <= sk) {
                const float4 u = *(const float4*)(src + (size_t)row * sk + c);
                h4 t; t[0] = (_Float16)u.x; t[1] = (_Float16)u.y;
                      t[2] = (_Float16)u.z; t[3] = (_Float16)u.w;
                *(h4*)(dst + (size_t)row * dk + c) = t;
            } else {
#pragma unroll
                for (int jj = 0; jj < 4; ++jj) {
                    const int cc = c + jj;
                    if (cc < dk)
                        dst[(size_t)row * dk + cc] =
                            (cc < sk) ? (_Float16)src[(size_t)row * sk + cc]
                                      : (_Float16)0.f;
                }
            }
        }
    }
}

// ---------------------------------------------------------------------------
// gemm_f16: C[M,Ncols] = act(A[M,Ka] @ W[Ncols,Ka]^T + b1 (+b2)); A,W f16,
// C f32. Same proven tile (BM128 x BN64, BK64, 4 waves), same MFMA layout and
// epilogue as the session's gemm_mfma; staging is pure half8 load -> half8
// LDS store (no f32->f16 VALU conversion — that was K1/K5's bottleneck).
// Ka must be a multiple of 64 (inputs pre-padded with zeros by cvt_rows).
// ---------------------------------------------------------------------------
#define BM 128
#define BN 64
#define BK 64
#define LDK 88

template<int ACT>
__global__ __launch_bounds__(256) void gemm_f16(
    const _Float16* __restrict__ A, const _Float16* __restrict__ W,
    const float* __restrict__ b1, const float* __restrict__ b2,
    float* __restrict__ C, int M, int Ka, int Ncols)
{
    __shared__ _Float16 As[BM][LDK];
    __shared__ _Float16 Ws[BN][LDK];

    const int tid  = threadIdx.x;
    const int wave = tid >> 6;
    const int lane = tid & 63;
    const int r    = lane & 15;
    const int q    = lane >> 4;
    const int m0   = blockIdx.y * BM;
    const int n0   = blockIdx.x * BN;
    const int wm   = (wave >> 1) * 64;
    const int wn   = (wave & 1) * 32;

    const int r32 = tid >> 3;        // staging row sub-index 0..31
    const int c8  = (tid & 7) * 8;   // staging k-offset (f16 elems)

    f32x4 acc[4][2];
#pragma unroll
    for (int i = 0; i < 4; ++i)
#pragma unroll
        for (int j = 0; j < 2; ++j) acc[i][j] = f32x4{0.f, 0.f, 0.f, 0.f};

    for (int kc = 0; kc < Ka; kc += BK) {
        // ---- stage A: 128 rows; 4 iters of 32 rows, half8 per thread
#pragma unroll
        for (int it = 0; it < 4; ++it) {
            const int row = it * 32 + r32;
            *(half8*)&As[row][c8] =
                *(const half8*)(A + (size_t)(m0 + row) * Ka + kc + c8);
        }
        // ---- stage W: 64 rows; 2 iters of 32 rows
#pragma unroll
        for (int it = 0; it < 2; ++it) {
            const int row  = it * 32 + r32;
            const int wrow = n0 + row;
            half8 t = {};
            if (wrow < Ncols)
                t = *(const half8*)(W + (size_t)wrow * Ka + kc + c8);
            *(half8*)&Ws[row][c8] = t;
        }
        __syncthreads();

        // ---- MFMA: two 32-k sub-chunks per buffer
#pragma unroll
        for (int s = 0; s < 2; ++s) {
            const int kb = s * 32 + q * 8;
            half8 af[4], wfr[2];
#pragma unroll
            for (int i = 0; i < 4; ++i)
                af[i] = *(const half8*)&As[wm + i * 16 + r][kb];
#pragma unroll
            for (int j = 0; j < 2; ++j)
                wfr[j] = *(const half8*)&Ws[wn + j * 16 + r][kb];
#pragma unroll
            for (int i = 0; i < 4; ++i)
#pragma unroll
                for (int j = 0; j < 2; ++j)
                    acc[i][j] = __builtin_amdgcn_mfma_f32_16x16x32_f16(
                        af[i], wfr[j], acc[i][j], 0, 0, 0);
        }
        __syncthreads();
    }

    // ---- epilogue: row=(lane>>4)*4+reg, col=lane&15 (m89/m91 layout)
#pragma unroll
    for (int i = 0; i < 4; ++i) {
#pragma unroll
        for (int j = 0; j < 2; ++j) {
            const int col = n0 + wn + j * 16 + r;
            if (col < Ncols) {
                const float bias = b1[col] + (b2 ? b2[col] : 0.f);
#pragma unroll
                for (int reg = 0; reg < 4; ++reg) {
                    const int row = m0 + wm + i * 16 + q * 4 + reg;
                    float v = acc[i][j][reg] + bias;
                    if (ACT == 1) v = fast_sigmoid(v);
                    C[(size_t)row * Ncols + col] = v;
                }
            }
        }
    }
}

// ---------------------------------------------------------------------------
// lstm_mega: R6-VERBATIM (the proven 804us pipeline: two-block-per-chain,
// CH=40, h1 f16 handoff, threadfence-release + acquire-poll), with ONE
// change: h2seq is written as f16 so K5 can read it without conversion
// (value identical — the old K5 staged f32->f16 anyway).
// R8 post-mortem (batched 8-CU pipeline, 1730us): per-step vmcnt(0) barrier
// drains exposed the scattered p-load latency, and 68 acquire-polling blocks
// generated buffer_inv storms that thrashed the rec blocks' L2. Reverted.
// ---------------------------------------------------------------------------
__global__ __launch_bounds__(256, 1) void lstm_mega(
    const float* __restrict__ pre1, const float* __restrict__ states_in,
    const float* __restrict__ Whh1, const float* __restrict__ Whh2,
    const float* __restrict__ Wih2, const float* __restrict__ bih2,
    const float* __restrict__ bhh2,
    _Float16* __restrict__ h1g,        // [M][128] f16 handoff (mask region)
    _Float16* __restrict__ h2seq,      // [M][128] f16 (bufB) for K5
    float* __restrict__ states_out, int* __restrict__ flags)
{
    const int layer = blockIdx.x >> 6;
    const int n     = blockIdx.x & 63;
    const int tid   = threadIdx.x;
    const int w     = tid >> 6;
    const int lane  = tid & 63;
    const int r     = lane & 15;
    const int q     = lane >> 4;
    const int b     = q & 1;
    const int j     = 32 * w + 16 * b + r;   // this lane's output index
    const int h_row0 = layer ? 128 : 0;

    __shared__ __align__(16) _Float16 hbuf[2][HID];
    // pre2 chunk, layer-2 blocks only. +4 pad: conflict-free reads.
    __shared__ __align__(16) float pre2ck[CH][GATES + 4];

    // ---- recurrence weights: wf[g][b2][s], row = 128g + 32w + 16b2 + r
    const float* Whh = layer ? Whh2 : Whh1;
    half8 wf[4][2][4];
#pragma unroll
    for (int g = 0; g < 4; ++g)
#pragma unroll
        for (int b2 = 0; b2 < 2; ++b2) {
            const float* src = Whh + (size_t)(128 * g + 32 * w + 16 * b2 + r) * HID + q * 8;
#pragma unroll
            for (int s = 0; s < 4; ++s) wf[g][b2][s] = cvt8(src + s * 32);
        }

    // ---- layer-2 extra: Wih2 B-frags (wave w owns pre2 cols 128w..128w+127)
    half8 wih[8][4];
    float bias2v[8];
    if (layer == 1) {
#pragma unroll
        for (int fi = 0; fi < 8; ++fi) {
            const int row = 128 * w + 16 * fi + r;
            const float* src = Wih2 + (size_t)row * HID + q * 8;
#pragma unroll
            for (int s = 0; s < 4; ++s) wih[fi][s] = cvt8(src + s * 32);
            bias2v[fi] = bih2[row] + bhh2[row];
        }
    }

    float c_r = states_in[(size_t)(h_row0 + 64 + n) * HID + j];
    if (tid < HID)
        hbuf[0][tid] = (_Float16)states_in[(size_t)(h_row0 + n) * HID + tid];
    __syncthreads();

    // layer-1: pre1 prefetch registers
    const float* pre_n = pre1 + (size_t)n * TSEQ * GATES;
    float pc0 = 0.f, pc1 = 0.f, pc2 = 0.f, pc3 = 0.f;
    float pn0 = 0.f, pn1 = 0.f, pn2 = 0.f, pn3 = 0.f;
    if (layer == 0) {
        pc0 = pre_n[j];           pc1 = pre_n[j + 128];
        pc2 = pre_n[j + 256];     pc3 = pre_n[j + 384];
        pn0 = pre_n[GATES + j];       pn1 = pre_n[GATES + j + 128];
        pn2 = pre_n[GATES + j + 256]; pn3 = pre_n[GATES + j + 384];
    }

    const f32x4 Z = {0.f, 0.f, 0.f, 0.f};
    int cur = 0, ts = 0, ck = 0;   // step-within-chunk, chunk index

    for (int t = 0; t < TSEQ; ++t) {
        // ==== layer-2 chunk head: wait for h1 chunk ck, compute pre2ck ====
        if (layer == 1 && ts == 0) {
            wait_flag(flags + n, ck + 1);    // ACQUIRE: h1g chunk ck visible
            const _Float16* hbase = h1g + ((size_t)n * TSEQ + (size_t)ck * CH) * HID;
#pragma unroll
            for (int mt = 0; mt < 3; ++mt) {
                const int mrow = (mt < 2) ? (mt * 16 + r) : (32 + (r & 7));
                const _Float16* src = hbase + (size_t)mrow * HID + q * 8;
                half8 ax[4];
#pragma unroll
                for (int s = 0; s < 4; ++s)
                    ax[s] = *(const half8*)(src + s * 32);
                f32x4 gacc[8];
#pragma unroll
                for (int fi = 0; fi < 8; ++fi)
                    gacc[fi] = __builtin_amdgcn_mfma_f32_16x16x32_f16(
                        ax[0], wih[fi][0], Z, 0, 0, 0);
#pragma unroll
                for (int s = 1; s < 4; ++s)
#pragma unroll
                    for (int fi = 0; fi < 8; ++fi)
                        gacc[fi] = __builtin_amdgcn_mfma_f32_16x16x32_f16(
                            ax[s], wih[fi][s], gacc[fi], 0, 0, 0);
                if (mt < 2 || q < 2) {
#pragma unroll
                    for (int fi = 0; fi < 8; ++fi)
#pragma unroll
                        for (int reg = 0; reg < 4; ++reg)
                            pre2ck[mt * 16 + 4 * q + reg][128 * w + 16 * fi + r] =
                                gacc[fi][reg] + bias2v[fi];
                }
            }
            __syncthreads();
        }

        // ==== gate pre-activations ====
        float p0, p1, p2, p3;
        if (layer == 0) {
            p0 = pc0; p1 = pc1; p2 = pc2; p3 = pc3;
            pc0 = pn0; pc1 = pn1; pc2 = pn2; pc3 = pn3;
            if (t + 2 < TSEQ) {
                const float* pp = pre_n + (size_t)(t + 2) * GATES + j;
                pn0 = pp[0]; pn1 = pp[128]; pn2 = pp[256]; pn3 = pp[384];
            }
        } else {
            p0 = pre2ck[ts][j];
            p1 = pre2ck[ts][j + 128];
            p2 = pre2ck[ts][j + 256];
            p3 = pre2ck[ts][j + 384];
        }

        // ==== recurrent matvec (MFMA) ====
        half8 hx[4];
#pragma unroll
        for (int s = 0; s < 4; ++s)
            hx[s] = *(const half8*)&hbuf[cur][s * 32 + q * 8];

        f32x4 acc[4][2];
#pragma unroll
        for (int g = 0; g < 4; ++g)
#pragma unroll
            for (int b2 = 0; b2 < 2; ++b2)
                acc[g][b2] = __builtin_amdgcn_mfma_f32_16x16x32_f16(
                    hx[0], wf[g][b2][0], Z, 0, 0, 0);
#pragma unroll
        for (int s = 1; s < 4; ++s)
#pragma unroll
            for (int g = 0; g < 4; ++g)
#pragma unroll
                for (int b2 = 0; b2 < 2; ++b2)
                    acc[g][b2] = __builtin_amdgcn_mfma_f32_16x16x32_f16(
                        hx[s], wf[g][b2][s], acc[g][b2], 0, 0, 0);

        const float A0 = (b ? acc[0][1][0] : acc[0][0][0]) + p0;
        const float A1 = (b ? acc[1][1][0] : acc[1][0][0]) + p1;
        const float A2 = (b ? acc[2][1][0] : acc[2][0][0]) + p2;
        const float A3 = (b ? acc[3][1][0] : acc[3][0][0]) + p3;

        const float gi = fast_sigmoid(A0);
        const float gf = fast_sigmoid(A1);
        const float gg = fast_tanh(A2);
        const float go = fast_sigmoid(A3);

        const float cn = gf * c_r + gi * gg;
        const float hh = go * fast_tanh(cn);
        c_r = cn;

        // ==== state writes ====
        if (q < 2) {
            hbuf[cur ^ 1][j] = (_Float16)hh;
            if (t == TSEQ - 1)
                states_out[(size_t)(h_row0 + 64 + n) * HID + j] = cn;
        } else {
            if (layer == 0)
                h1g[((size_t)n * TSEQ + t) * HID + j] = (_Float16)hh;
            else
                h2seq[((size_t)n * TSEQ + t) * HID + j] = (_Float16)hh;
            if (t == TSEQ - 1)
                states_out[(size_t)(h_row0 + n) * HID + j] = hh;
        }
        __syncthreads();   // drains vmcnt(0) per wave: chunk stores complete

        // ==== layer-1 chunk tail: publish chunk ck (proven fence recipe) ====
        if (layer == 0 && ts == CH - 1 && tid == 0) {
            __threadfence();   // agent release (wbl2): h1g chunk ck visible
            __hip_atomic_store(flags + n, ck + 1,
                               __ATOMIC_RELAXED, __HIP_MEMORY_SCOPE_AGENT);
        }

        if (++ts == CH) { ts = 0; ++ck; }
        cur ^= 1;
    }
}

// ---------------------------------------------------------------------------
extern "C" void kernel_launch(void* const* d_in, const int* in_sizes, int n_in,
                              void* d_out, int out_size, void* d_ws, size_t ws_size,
                              hipStream_t stream)
{
    const float* x     = (const float*)d_in[0];
    const float* st_in = (const float*)d_in[1];
    const float* Wih1  = (const float*)d_in[2];
    const float* Whh1  = (const float*)d_in[3];
    const float* bih1  = (const float*)d_in[4];
    const float* bhh1  = (const float*)d_in[5];
    const float* Wih2  = (const float*)d_in[6];
    const float* Whh2  = (const float*)d_in[7];
    const float* bih2  = (const float*)d_in[8];
    const float* bhh2  = (const float*)d_in[9];
    const float* Wd    = (const float*)d_in[10];
    const float* bd    = (const float*)d_in[11];

    float* out_mask   = (float*)d_out;
    float* out_states = (float*)d_out + (size_t)NBATCH * TSEQ * DIN;

    const int M = NBATCH * TSEQ;
    float* bufA = (float*)d_ws;               // [M,512] f32 pre1
    float* bufB = bufA + (size_t)M * GATES;   // h2seq f16 + converted weights

    // bufB carve-up: h2seq f16 [M][128] (16.4MB), then Wih1h, then Wdh.
    _Float16* h2seq = (_Float16*)bufB;
    _Float16* wih1h = h2seq + (size_t)M * HID;            // [512][320]
    _Float16* wdh   = wih1h + (size_t)GATES * KP1;        // [257][128]

    // mask-region carve-up (overwritten by K5 strictly afterwards):
    //   xh f16 [M][320] (41MB), h1g f16 [M][128] (16.4MB), flags at tail.
    _Float16* xh  = (_Float16*)out_mask;
    _Float16* h1g = xh + (size_t)M * KP1;
    int* flags = (int*)(out_mask + (size_t)NBATCH * TSEQ * DIN) - 64;
    hipMemsetAsync(flags, 0, 64 * sizeof(int), stream);

    // K0: f32 -> f16 conversions (memory-bound, ~18us total)
    cvt_rows<<<256, 256, 0, stream>>>(x,    xh,    M,     DIN, KP1);
    cvt_rows<<<8,   256, 0, stream>>>(Wih1, wih1h, GATES, DIN, KP1);
    cvt_rows<<<8,   256, 0, stream>>>(Wd,   wdh,   DIN,   HID, HID);

    // K1: pre1 = xh @ Wih1h^T + bih1 + bhh1   (f16 in, M=64000, Ka=320)
    gemm_f16<0><<<dim3(GATES / BN, M / BM), 256, 0, stream>>>(
        xh, wih1h, bih1, bhh1, bufA, M, KP1, GATES);

    // K2: fused pipelined L1 rec -> h1 handoff -> (pre2 on reader) -> L2 rec
    lstm_mega<<<128, 256, 0, stream>>>(
        bufA, st_in, Whh1, Whh2, Wih2, bih2, bhh2, h1g, h2seq, out_states, flags);

    // K5: mask = sigmoid(h2seq @ Wdh^T + bd)   (f16 in, Ka=128, N=257)
    gemm_f16<1><<<dim3((DIN + BN - 1) / BN, M / BM), 256, 0, stream>>>(
        h2seq, wdh, bd, nullptr, out_mask, M, HID, DIN);
}